// Round 1
// baseline (3290.990 us; speedup 1.0000x reference)
//
#include <hip/hip_runtime.h>

#define NB   32
#define NSUP 25
#define NC   512
#define NHW  196
#define NDK  128
#define NPT  4900   // NSUP*NHW

// ---------------------------------------------------------------------------
// Kernel 1: projections.  grid = NB*(NSUP+1) blocks, 256 threads.
// Each block: OUT[256 d][196 p] = Wcat[256x512] @ X[512x196] for one (b,n)
// (n==NSUP means the query image).  K rows of OUT (d<128) -> sk (d-major),
// V rows -> sv (p-major).  Thread t: d-group (t>>2)*4, j-group (t&3)*7,
// p processed in 7 chunks of 28 with X chunk staged in LDS.
// ---------------------------------------------------------------------------
__global__ __launch_bounds__(256) void k_proj(
    const float* __restrict__ query, const float* __restrict__ supports,
    const float* __restrict__ Wqk, const float* __restrict__ Wv,
    float* __restrict__ sk, float* __restrict__ sv,
    float* __restrict__ qq, float* __restrict__ qv)
{
    __shared__ float Xs[NC][28];
    const int bid = blockIdx.x;
    const int b = bid / (NSUP + 1);
    const int n = bid % (NSUP + 1);
    const float* X = (n < NSUP)
        ? (supports + (size_t)(b * NSUP + n) * NC * NHW)
        : (query + (size_t)b * NC * NHW);
    const int t  = threadIdx.x;
    const int j0 = (t & 3) * 7;   // j-group within 28-col chunk
    const int d0 = (t >> 2) * 4;  // 4 output rows per thread

    const float* wrow[4];
#pragma unroll
    for (int dd = 0; dd < 4; ++dd) {
        int d = d0 + dd;
        wrow[dd] = (d < NDK) ? (Wqk + (size_t)d * NC) : (Wv + (size_t)(d - NDK) * NC);
    }

    for (int pc = 0; pc < 7; ++pc) {
        const int p0 = pc * 28;
        __syncthreads();
        for (int idx = t; idx < NC * 28; idx += 256) {
            int k = idx / 28, j = idx - k * 28;
            Xs[k][j] = X[(size_t)k * NHW + p0 + j];
        }
        __syncthreads();

        float acc[4][7];
#pragma unroll
        for (int dd = 0; dd < 4; ++dd)
#pragma unroll
            for (int jj = 0; jj < 7; ++jj) acc[dd][jj] = 0.f;

        for (int k = 0; k < NC; k += 4) {
            float4 w4[4];
#pragma unroll
            for (int dd = 0; dd < 4; ++dd) w4[dd] = *(const float4*)(wrow[dd] + k);
#pragma unroll
            for (int kk = 0; kk < 4; ++kk) {
                float xv[7];
#pragma unroll
                for (int jj = 0; jj < 7; ++jj) xv[jj] = Xs[k + kk][j0 + jj];
#pragma unroll
                for (int dd = 0; dd < 4; ++dd) {
                    const float w = ((const float*)&w4[dd])[kk];
#pragma unroll
                    for (int jj = 0; jj < 7; ++jj)
                        acc[dd][jj] = fmaf(w, xv[jj], acc[dd][jj]);
                }
            }
        }

        if (n < NSUP) {
            const int pg = n * NHW + p0 + j0;
#pragma unroll
            for (int dd = 0; dd < 4; ++dd) {
                const int d = d0 + dd;
#pragma unroll
                for (int jj = 0; jj < 7; ++jj) {
                    const int p = pg + jj;
                    if (d < NDK) sk[((size_t)b * NDK + d) * NPT + p] = acc[dd][jj];
                    else         sv[((size_t)b * NPT + p) * NDK + (d - NDK)] = acc[dd][jj];
                }
            }
        } else {
#pragma unroll
            for (int dd = 0; dd < 4; ++dd) {
                const int d = d0 + dd;
#pragma unroll
                for (int jj = 0; jj < 7; ++jj) {
                    const int s = p0 + j0 + jj;
                    if (d < NDK) qq[((size_t)b * NHW + s) * NDK + d] = acc[dd][jj];
                    else         qv[((size_t)b * NHW + s) * NDK + (d - NDK)] = acc[dd][jj];
                }
            }
        }
    }
}

// ---------------------------------------------------------------------------
// Kernel 2: sim[b][s][p] = sum_k qq[b][s][k] * sk[b][k][p]
// grid (77 p-tiles of 64, 5 s-tiles of 48, 32 b), 256 threads.
// Thread computes 3s x 4p register tile.  Qs transposed [k][s] (pad 52,
// conflict-free b32 reads), Ks [k][p] (b128 reads, bank-clean).
// ---------------------------------------------------------------------------
__global__ __launch_bounds__(256) void k_sim(
    const float* __restrict__ qq, const float* __restrict__ sk,
    float* __restrict__ sim)
{
    __shared__ __align__(16) float Qs[128][52];
    __shared__ __align__(16) float Ks[128][64];
    const int b  = blockIdx.z;
    const int s0 = blockIdx.y * 48;
    const int p0 = blockIdx.x * 64;
    const int t  = threadIdx.x;

    for (int idx = t; idx < 48 * 128; idx += 256) {
        const int s = idx >> 7, k = idx & 127;
        const int sg = s0 + s;
        Qs[k][s] = (sg < NHW) ? qq[((size_t)b * NHW + sg) * NDK + k] : 0.f;
    }
    for (int idx = t; idx < 128 * 64; idx += 256) {
        const int k = idx >> 6, pp = idx & 63;
        const int pg = p0 + pp;
        Ks[k][pp] = (pg < NPT) ? sk[((size_t)b * NDK + k) * NPT + pg] : 0.f;
    }
    __syncthreads();

    const int ss = (t & 15) * 3;
    const int pp = (t >> 4) * 4;
    float acc[3][4];
#pragma unroll
    for (int i = 0; i < 3; ++i)
#pragma unroll
        for (int j = 0; j < 4; ++j) acc[i][j] = 0.f;

#pragma unroll 4
    for (int k = 0; k < 128; ++k) {
        const float q0 = Qs[k][ss];
        const float q1 = Qs[k][ss + 1];
        const float q2 = Qs[k][ss + 2];
        const float4 kv = *(const float4*)&Ks[k][pp];
        acc[0][0] = fmaf(q0, kv.x, acc[0][0]);
        acc[0][1] = fmaf(q0, kv.y, acc[0][1]);
        acc[0][2] = fmaf(q0, kv.z, acc[0][2]);
        acc[0][3] = fmaf(q0, kv.w, acc[0][3]);
        acc[1][0] = fmaf(q1, kv.x, acc[1][0]);
        acc[1][1] = fmaf(q1, kv.y, acc[1][1]);
        acc[1][2] = fmaf(q1, kv.z, acc[1][2]);
        acc[1][3] = fmaf(q1, kv.w, acc[1][3]);
        acc[2][0] = fmaf(q2, kv.x, acc[2][0]);
        acc[2][1] = fmaf(q2, kv.y, acc[2][1]);
        acc[2][2] = fmaf(q2, kv.z, acc[2][2]);
        acc[2][3] = fmaf(q2, kv.w, acc[2][3]);
    }

#pragma unroll
    for (int si = 0; si < 3; ++si) {
        const int s = s0 + ss + si;
        if (s >= NHW) continue;
#pragma unroll
        for (int pj = 0; pj < 4; ++pj) {
            const int p = p0 + pp + pj;
            if (p < NPT) sim[((size_t)b * NHW + s) * NPT + p] = acc[si][pj];
        }
    }
}

// ---------------------------------------------------------------------------
// Kernel 3: softmax over p + out = attn @ SV + distance accumulation.
// grid (7 s-tiles of 28, 32 b), 256 threads.  Per-wave row max/sum, then
// P staged transposed in LDS per 256-p tile, PV with thread = (d, p-parity),
// epilogue computes (qv - out)^2 partial and atomicAdds the scalar.
// ---------------------------------------------------------------------------
__global__ __launch_bounds__(256) void k_attn(
    const float* __restrict__ sim, const float* __restrict__ sv,
    const float* __restrict__ qv, float* __restrict__ out)
{
    __shared__ __align__(16) float Plds[256][36];
    __shared__ float comb[28][128];
    __shared__ float rowmax[28];
    __shared__ float rowsum[28];
    __shared__ float wpart[4];
    const int b  = blockIdx.y;
    const int s0 = blockIdx.x * 28;
    const int t  = threadIdx.x;
    const int w  = t >> 6, lane = t & 63;

    // phase 1+2: per-wave rows (wave w owns rows w*7 .. w*7+6)
    for (int r7 = 0; r7 < 7; ++r7) {
        const int r = w * 7 + r7;
        const float* srow = sim + ((size_t)b * NHW + s0 + r) * NPT;
        float m = -1e30f;
        for (int p = lane; p < NPT; p += 64) m = fmaxf(m, srow[p]);
#pragma unroll
        for (int off = 32; off > 0; off >>= 1) m = fmaxf(m, __shfl_down(m, off, 64));
        m = __shfl(m, 0, 64);
        float ssum = 0.f;
        for (int p = lane; p < NPT; p += 64) ssum += __expf(srow[p] - m);
#pragma unroll
        for (int off = 32; off > 0; off >>= 1) ssum += __shfl_down(ssum, off, 64);
        if (lane == 0) { rowmax[r] = m; rowsum[r] = ssum; }
    }
    __syncthreads();

    // phase 3: PV accumulation
    const int d  = t & 127;
    const int pi = t >> 7;
    float acc[28];
#pragma unroll
    for (int r = 0; r < 28; ++r) acc[r] = 0.f;

    for (int pt = 0; pt < NPT; pt += 256) {
        const int tl = min(256, NPT - pt);
        __syncthreads();
        if (t < tl) {
#pragma unroll 4
            for (int r = 0; r < 28; ++r) {
                Plds[t][r] = __expf(sim[((size_t)b * NHW + s0 + r) * NPT + pt + t]
                                    - rowmax[r]);
            }
        }
        __syncthreads();
        for (int j = pi; j < tl; j += 2) {
            const float svv = sv[((size_t)b * NPT + pt + j) * NDK + d];
            const float4* prow = (const float4*)&Plds[j][0];
#pragma unroll
            for (int r4 = 0; r4 < 7; ++r4) {
                const float4 pv = prow[r4];
                acc[r4 * 4 + 0] = fmaf(pv.x, svv, acc[r4 * 4 + 0]);
                acc[r4 * 4 + 1] = fmaf(pv.y, svv, acc[r4 * 4 + 1]);
                acc[r4 * 4 + 2] = fmaf(pv.z, svv, acc[r4 * 4 + 2]);
                acc[r4 * 4 + 3] = fmaf(pv.w, svv, acc[r4 * 4 + 3]);
            }
        }
    }

    __syncthreads();
    if (pi == 1) {
#pragma unroll
        for (int r = 0; r < 28; ++r) comb[r][d] = acc[r];
    }
    __syncthreads();

    float part = 0.f;
    if (pi == 0) {
#pragma unroll
        for (int r = 0; r < 28; ++r) {
            const float o = (acc[r] + comb[r][d]) / rowsum[r];
            const float q = qv[((size_t)b * NHW + s0 + r) * NDK + d];
            const float diff = q - o;
            part = fmaf(diff, diff, part);
        }
    }
#pragma unroll
    for (int off = 32; off > 0; off >>= 1) part += __shfl_down(part, off, 64);
    if (lane == 0) wpart[w] = part;
    __syncthreads();
    if (t == 0) {
        atomicAdd(out, (wpart[0] + wpart[1] + wpart[2] + wpart[3]) * (1.0f / 196.0f));
    }
}

// ---------------------------------------------------------------------------
extern "C" void kernel_launch(void* const* d_in, const int* in_sizes, int n_in,
                              void* d_out, int out_size, void* d_ws, size_t ws_size,
                              hipStream_t stream)
{
    const float* query    = (const float*)d_in[0];  // [32,512,14,14]
    const float* supports = (const float*)d_in[1];  // [32,25,512,14,14]
    const float* Wqk      = (const float*)d_in[2];  // [128,512]
    const float* Wv       = (const float*)d_in[3];  // [128,512]
    float* out = (float*)d_out;

    // workspace layout (floats):
    float* ws  = (float*)d_ws;
    float* sk  = ws;                                   // [32][128][4900]
    float* sv  = sk + (size_t)NB * NDK * NPT;          // [32][4900][128]
    float* qq  = sv + (size_t)NB * NPT * NDK;          // [32][196][128]
    float* qv  = qq + (size_t)NB * NHW * NDK;          // [32][196][128]
    float* sim = qv + (size_t)NB * NHW * NDK;          // [32][196][4900]

    hipMemsetAsync(d_out, 0, (size_t)out_size * sizeof(float), stream);

    k_proj<<<NB * (NSUP + 1), 256, 0, stream>>>(query, supports, Wqk, Wv,
                                                sk, sv, qq, qv);
    k_sim<<<dim3(77, 5, NB), 256, 0, stream>>>(qq, sk, sim);
    k_attn<<<dim3(7, NB), 256, 0, stream>>>(sim, sv, qv, out);
}

// Round 2
// 765.071 us; speedup vs baseline: 4.3015x; 4.3015x over previous
//
#include <hip/hip_runtime.h>

#define NB   32
#define NSUP 25
#define NC   512
#define NHW  196
#define NDK  128
#define NPT  4900      // NSUP*NHW
#define NPTP 4928      // padded (77 chunks of 64), zeroed pad for k_attn B-frags

typedef short  bf16x8 __attribute__((ext_vector_type(8)));
typedef float  f32x4  __attribute__((ext_vector_type(4)));
typedef float  f32x4v __attribute__((ext_vector_type(4)));
typedef unsigned short ushort;
typedef unsigned int   uint;
typedef ushort ushort4v __attribute__((ext_vector_type(4)));
typedef uint   uint2v   __attribute__((ext_vector_type(2)));

static __device__ __forceinline__ ushort f2bf(float f) {
    union { float f; uint u; } v; v.f = f;
    uint r = v.u + 0x7fffu + ((v.u >> 16) & 1u);   // RNE
    return (ushort)(r >> 16);
}

static __device__ __forceinline__ f32x4 mfma16(bf16x8 a, bf16x8 b, f32x4 c) {
    return __builtin_amdgcn_mfma_f32_16x16x32_bf16(a, b, c, 0, 0, 0);
}

// ---------------------------------------------------------------------------
// k_cast: Wqk[128x512] + Wv[128x512] fp32 -> Wc[256x512] bf16 (rows 0-127 = K)
// ---------------------------------------------------------------------------
__global__ __launch_bounds__(256) void k_cast(
    const float* __restrict__ Wqk, const float* __restrict__ Wv,
    ushort* __restrict__ Wc)
{
    int i = blockIdx.x * 256 + threadIdx.x;            // float4 index, < 32768
    const float* src = (i < 16384) ? Wqk : Wv;
    int j = (i < 16384) ? i : i - 16384;
    f32x4 v = *(const f32x4*)(src + (size_t)j * 4);
    ushort4v u;
    u[0] = f2bf(v[0]); u[1] = f2bf(v[1]); u[2] = f2bf(v[2]); u[3] = f2bf(v[3]);
    *(ushort4v*)(Wc + (size_t)i * 4) = u;
}

// ---------------------------------------------------------------------------
// k_zpad: zero sv[b][d][4900..4928) so padded K-slices in k_attn are 0*P=0.
// ---------------------------------------------------------------------------
__global__ __launch_bounds__(256) void k_zpad(ushort* __restrict__ sv)
{
    int i = blockIdx.x * 256 + threadIdx.x;            // < 4096*14 uint words
    if (i < 4096 * 14) {
        int row = i / 14, j = i - row * 14;
        ((uint*)sv)[(size_t)row * (NPTP / 2) + (NPT / 2) + j] = 0u;
    }
}

// ---------------------------------------------------------------------------
// k_proj: per (b, n, p-half): OUT[256 d][PW p] = Wc[256x512] @ X[512xPW]
// 512 threads = 8 waves, wave w owns d-rows [32w, 32w+32).
// X staged in LDS transposed to [p][64 k] bf16 with XOR-chunk swizzle.
// Outputs: sk[b][p][d] bf16, sv[b][d][p] bf16, qq[b][s][d] bf16, qv fp32.
// ---------------------------------------------------------------------------
template<int PBASE, int NT, int PG>
__global__ __launch_bounds__(512) void k_proj(
    const float* __restrict__ query, const float* __restrict__ supports,
    const ushort* __restrict__ Wc,
    ushort* __restrict__ sk, ushort* __restrict__ sv,
    ushort* __restrict__ qq, float* __restrict__ qv)
{
    __shared__ __align__(16) ushort Xl[112 * 64];
    const int n = blockIdx.x;
    const int b = blockIdx.y;
    const float* X = (n < NSUP)
        ? (supports + (size_t)(b * NSUP + n) * NC * NHW)
        : (query + (size_t)b * NC * NHW);
    const int t = threadIdx.x;
    const int w = t >> 6, l = t & 63;
    const int m0 = w * 32;
    const int l15 = l & 15, l4 = l >> 4;

    f32x4 acc[2][NT];
#pragma unroll
    for (int mi = 0; mi < 2; ++mi)
#pragma unroll
        for (int nt = 0; nt < NT; ++nt) acc[mi][nt] = (f32x4){0.f, 0.f, 0.f, 0.f};

    for (int kt = 0; kt < NC; kt += 64) {
        if (kt) __syncthreads();
        // ---- stage: X[kt..kt+64)[PBASE..PBASE+PG*4) -> Xl[p_local][k] bf16
        for (int pass = 0; pass < 2; ++pass) {
            int idx = t + pass * 512;
            if (idx < 32 * PG) {
                int kp = idx / PG;                 // k-pair 0..31
                int pg = idx - kp * PG;            // p-group (4 p)
                const float* r0 = X + (size_t)(kt + 2 * kp) * NHW + PBASE + pg * 4;
                f32x4 f0 = *(const f32x4*)r0;
                f32x4 f1 = *(const f32x4*)(r0 + NHW);
                int cq = kp >> 2;                  // 16B chunk 0..7
#pragma unroll
                for (int j = 0; j < 4; ++j) {
                    int p = pg * 4 + j;
                    uint wd = (uint)f2bf(f0[j]) | ((uint)f2bf(f1[j]) << 16);
                    ((uint*)Xl)[p * 32 + ((cq ^ (p & 7)) << 2) + (kp & 3)] = wd;
                }
            }
        }
        __syncthreads();
        // ---- compute
#pragma unroll
        for (int kkh = 0; kkh < 2; ++kkh) {
            const ushort* wrow = Wc + (size_t)(m0 + l15) * NC + kt + kkh * 32 + l4 * 8;
            bf16x8 a0 = *(const bf16x8*)wrow;
            bf16x8 a1 = *(const bf16x8*)(wrow + 16 * NC);
#pragma unroll
            for (int nt = 0; nt < NT; ++nt) {
                int p = nt * 16 + l15;
                int cq = kkh * 4 + l4;
                bf16x8 bf = *(const bf16x8*)&Xl[p * 64 + ((cq ^ (p & 7)) << 3)];
                acc[0][nt] = mfma16(a0, bf, acc[0][nt]);
                acc[1][nt] = mfma16(a1, bf, acc[1][nt]);
            }
        }
    }

    // ---- epilogue: D col p = l15 (+tile), rows d = m0+mi*16+l4*4+r
#pragma unroll
    for (int nt = 0; nt < NT; ++nt) {
        int p = PBASE + nt * 16 + l15;
        if (p >= NHW) continue;
#pragma unroll
        for (int mi = 0; mi < 2; ++mi) {
            int dbase = m0 + mi * 16 + l4 * 4;
            f32x4 v = acc[mi][nt];
            if (n < NSUP) {
                int pgl = n * NHW + p;
                if (dbase < NDK) {
                    ushort4v u;
                    u[0] = f2bf(v[0]); u[1] = f2bf(v[1]);
                    u[2] = f2bf(v[2]); u[3] = f2bf(v[3]);
                    *(ushort4v*)&sk[((size_t)b * NPT + pgl) * NDK + dbase] = u;
                } else {
                    int dv = dbase - NDK;
#pragma unroll
                    for (int r = 0; r < 4; ++r)
                        sv[((size_t)b * NDK + dv + r) * NPTP + pgl] = f2bf(v[r]);
                }
            } else {
                if (dbase < NDK) {
                    ushort4v u;
                    u[0] = f2bf(v[0]); u[1] = f2bf(v[1]);
                    u[2] = f2bf(v[2]); u[3] = f2bf(v[3]);
                    *(ushort4v*)&qq[((size_t)b * NHW + p) * NDK + dbase] = u;
                } else {
                    *(f32x4*)&qv[((size_t)b * NHW + p) * NDK + (dbase - NDK)] = v;
                }
            }
        }
    }
}

// ---------------------------------------------------------------------------
// k_sim: sim[b][s][p] = sum_d qq[b][s][d] * sk[b][p][d]   (A=sk rows p, B=qq
// cols s, K=128).  256 thr / 4 waves; wave = one 16-p tile x 13 s-tiles.
// D regs = 4 consecutive p -> float4 stores.
// ---------------------------------------------------------------------------
__global__ __launch_bounds__(256) void k_sim(
    const ushort* __restrict__ qq, const ushort* __restrict__ sk,
    float* __restrict__ sim)
{
    const int b = blockIdx.y;
    const int t = threadIdx.x, l = t & 63;
    const int l15 = l & 15, l4 = l >> 4;
    const int pw = blockIdx.x * 64 + (t >> 6) * 16;

    int pA = pw + l15; if (pA > NPT - 1) pA = NPT - 1;
    const ushort* Ab = sk + ((size_t)b * NPT + pA) * NDK + l4 * 8;
    const ushort* Bb = qq + (size_t)b * NHW * NDK + l4 * 8;

    f32x4 acc[13];
#pragma unroll
    for (int st = 0; st < 13; ++st) acc[st] = (f32x4){0.f, 0.f, 0.f, 0.f};

#pragma unroll
    for (int k0 = 0; k0 < 128; k0 += 32) {
        bf16x8 a = *(const bf16x8*)(Ab + k0);
#pragma unroll
        for (int st = 0; st < 13; ++st) {
            int s = st * 16 + l15; if (s > NHW - 1) s = NHW - 1;
            bf16x8 bf = *(const bf16x8*)(Bb + (size_t)s * NDK + k0);
            acc[st] = mfma16(a, bf, acc[st]);
        }
    }

    int pst = pw + l4 * 4;
#pragma unroll
    for (int st = 0; st < 13; ++st) {
        int s = st * 16 + l15;
        if (s < NHW && pst + 3 < NPT)
            *(f32x4*)&sim[((size_t)b * NHW + s) * NPT + pst] = acc[st];
    }
}

// ---------------------------------------------------------------------------
// k_attn: fixed-shift softmax (exp(x-60), exact after normalization) + PV via
// MFMA + distance.  grid (13 s-tiles, 32 b), 256 thr / 4 waves.
// P staged [16 s][64 p] bf16 in LDS (stride 72: conflict-free), B from
// sv[b][d][p] (pad zeroed).  Normalization deferred to epilogue.
// ---------------------------------------------------------------------------
__global__ __launch_bounds__(256) void k_attn(
    const float* __restrict__ sim, const ushort* __restrict__ sv,
    const float* __restrict__ qv, float* __restrict__ out)
{
    __shared__ __align__(16) ushort Pl[16 * 72];
    __shared__ float rsP[16 * 16];
    __shared__ float rsum[16];
    __shared__ float wred[4];
    const int b = blockIdx.y;
    const int s0 = blockIdx.x * 16;
    const int t = threadIdx.x;
    const int w = t >> 6, l = t & 63;
    const int l15 = l & 15, l4 = l >> 4;
    const int sl = t >> 4;                 // staging row 0..15
    const int pq = (t & 15) * 4;           // staging col 0..60
    const int sg = s0 + sl;
    const bool srow_ok = (sg < NHW);
    const float* simrow = sim + ((size_t)b * NHW + (srow_ok ? sg : 0)) * NPT;
    const ushort* svb = sv + (size_t)b * NDK * NPTP;

    float psum = 0.f;
    f32x4 acc[2];
    acc[0] = (f32x4){0.f, 0.f, 0.f, 0.f};
    acc[1] = (f32x4){0.f, 0.f, 0.f, 0.f};

    for (int ch = 0; ch < 77; ++ch) {
        const int p0 = ch * 64;
        __syncthreads();
        // ---- stage P = exp(sim - 60) as bf16
        float e0 = 0.f, e1 = 0.f, e2 = 0.f, e3 = 0.f;
        if (srow_ok && (p0 + pq) < NPT) {
            f32x4 xv = *(const f32x4*)(simrow + p0 + pq);
            e0 = __expf(xv[0] - 60.f);
            e1 = __expf(xv[1] - 60.f);
            e2 = __expf(xv[2] - 60.f);
            e3 = __expf(xv[3] - 60.f);
            psum += e0 + e1 + e2 + e3;
        }
        uint2v wd;
        wd[0] = (uint)f2bf(e0) | ((uint)f2bf(e1) << 16);
        wd[1] = (uint)f2bf(e2) | ((uint)f2bf(e3) << 16);
        *(uint2v*)&Pl[sl * 72 + pq] = wd;
        __syncthreads();
        // ---- PV MFMA
        bf16x8 a0 = *(const bf16x8*)&Pl[l15 * 72 + l4 * 8];
        bf16x8 a1 = *(const bf16x8*)&Pl[l15 * 72 + 32 + l4 * 8];
#pragma unroll
        for (int nt = 0; nt < 2; ++nt) {
            int d = w * 32 + nt * 16 + l15;
            const ushort* svd = svb + (size_t)d * NPTP + p0 + l4 * 8;
            bf16x8 b0 = *(const bf16x8*)svd;
            bf16x8 b1 = *(const bf16x8*)(svd + 32);
            acc[nt] = mfma16(a0, b0, acc[nt]);
            acc[nt] = mfma16(a1, b1, acc[nt]);
        }
    }

    // ---- rowsum reduce
    rsP[sl * 16 + (t & 15)] = psum;
    __syncthreads();
    if (t < 16) {
        float s = 0.f;
#pragma unroll
        for (int j = 0; j < 16; ++j) s += rsP[t * 16 + j];
        rsum[t] = s;
    }
    __syncthreads();

    // ---- distance epilogue
    float part = 0.f;
#pragma unroll
    for (int nt = 0; nt < 2; ++nt) {
        int d = w * 32 + nt * 16 + l15;
#pragma unroll
        for (int r = 0; r < 4; ++r) {
            int sr = l4 * 4 + r;
            int s = s0 + sr;
            if (s < NHW) {
                float o = acc[nt][r] / rsum[sr];
                float q = qv[((size_t)b * NHW + s) * NDK + d];
                float df = q - o;
                part = fmaf(df, df, part);
            }
        }
    }
#pragma unroll
    for (int off = 32; off > 0; off >>= 1) part += __shfl_down(part, off, 64);
    if (l == 0) wred[w] = part;
    __syncthreads();
    if (t == 0)
        atomicAdd(out, (wred[0] + wred[1] + wred[2] + wred[3]) * (1.0f / 196.0f));
}

// ---------------------------------------------------------------------------
extern "C" void kernel_launch(void* const* d_in, const int* in_sizes, int n_in,
                              void* d_out, int out_size, void* d_ws, size_t ws_size,
                              hipStream_t stream)
{
    const float* query    = (const float*)d_in[0];
    const float* supports = (const float*)d_in[1];
    const float* Wqk      = (const float*)d_in[2];
    const float* Wv       = (const float*)d_in[3];
    float* out = (float*)d_out;

    char* ws = (char*)d_ws;
    ushort* Wc  = (ushort*)ws;                         ws += (size_t)256 * NC * 2;
    ushort* sk  = (ushort*)ws;                         ws += (size_t)NB * NPT * NDK * 2;
    ushort* sv  = (ushort*)ws;                         ws += (size_t)NB * NDK * NPTP * 2;
    ushort* qq  = (ushort*)ws;                         ws += (size_t)NB * NHW * NDK * 2;
    float*  qv  = (float*)ws;                          ws += (size_t)NB * NHW * NDK * 4;
    float*  sim = (float*)ws;

    hipMemsetAsync(d_out, 0, (size_t)out_size * sizeof(float), stream);
    k_cast<<<128, 256, 0, stream>>>(Wqk, Wv, Wc);
    k_zpad<<<224, 256, 0, stream>>>(sv);
    k_proj<0,   7, 28><<<dim3(NSUP + 1, NB), 512, 0, stream>>>(query, supports, Wc, sk, sv, qq, qv);
    k_proj<112, 6, 21><<<dim3(NSUP + 1, NB), 512, 0, stream>>>(query, supports, Wc, sk, sv, qq, qv);
    k_sim<<<dim3(77, NB), 256, 0, stream>>>(qq, sk, sim);
    k_attn<<<dim3(13, NB), 256, 0, stream>>>(sim, sv, qv, out);
}